// Round 5
// baseline (441.319 us; speedup 1.0000x reference)
//
#include <hip/hip_runtime.h>
#include <math.h>

// Problem constants (B=2, H=W=256, DIM=INNER=64, WS=8, OWS=12, HEADS=4, DH=16)
#define NPIX   65536      // 256*256
#define NPIXT  131072     // B * NPIX
#define NW     1024       // 32*32 windows per batch
#define KEEP   512

// Layouts: x, condition_global, h1, sa, out = NCHW (as given / required).
// qs, ks, vs, amix = NHWC: t[(b*NPIX + p)*64 + c]  (64 contiguous ch/pixel).
// xm = window-major: xm[(b<<16) + win*64 + (h&7)*8 + (w&7)]  (round-5 change).

// readlane broadcast helper: value from lane `l` of `v` (l may be runtime
// uniform -> SGPR lane select).  Result is wave-uniform (SGPR), consumed as
// the scalar operand of v_fmac -> zero LDS traffic for shared data.
__device__ __forceinline__ float bcast(float v, int l) {
    return __int_as_float(__builtin_amdgcn_readlane(__float_as_int(v), l));
}

// ---------------------------------------------------------------------------
// K1: fused q/k/v 1x1 convs.  ROUND-5: register-broadcast weights, NO LDS.
// Round-4 diagnosis: uniform ds_read_b128 "broadcasts" still return
// 16B x 64 lanes = 1KB on the LDS bus; k_qkv's weight reads totalled 6.4 GB
// -> 67 TB/s ~= the LDS ceiling -> LDS-BW-bound (VALUBusy 31%).
// Fix: wave loads its 16x64 weights ONCE, lane-distributed (w[j] holds
// W[wo+j][lane], coalesced 256B loads), then per channel c broadcasts via
// v_readlane into SGPRs consumed directly by v_fmac.  2 px per lane
// (float2 x loads) amortize the readlanes.  x tile (32KB) is L1-resident
// across the 3 m-passes.  Per (px,og,j) accumulation is ascending c 0..63
// -> bit-identical outputs.
// ---------------------------------------------------------------------------
__global__ __launch_bounds__(256) void k_qkv(
    const float* __restrict__ x,
    const float* __restrict__ Wq, const float* __restrict__ bq,
    const float* __restrict__ Wk, const float* __restrict__ bk,
    const float* __restrict__ Wv, const float* __restrict__ bv,
    float* __restrict__ qs, float* __restrict__ ks, float* __restrict__ vs)
{
    const int tid  = threadIdx.x;
    const int lane = tid & 63;
    const int og   = __builtin_amdgcn_readfirstlane(tid >> 6);  // wave-uniform
    const int tile = blockIdx.x;                 // 0..1023
    const int b    = tile >> 9;
    const int p0   = (tile & 511) << 7;          // 128-px tile
    const int p    = p0 + 2 * lane;
    const int gp   = (b << 16) + p;
    const int wo   = og * 16;

    const float* Ws[3]   = {Wq, Wk, Wv};
    const float* bias[3] = {bq, bk, bv};
    float* outs[3] = {qs + (size_t)gp * 64, ks + (size_t)gp * 64, vs + (size_t)gp * 64};
    const float* xg = x + ((size_t)b * 64) * NPIX + p;

    #pragma unroll
    for (int m = 0; m < 3; ++m) {
        const float* Wm = Ws[m];
        // lane-distributed weight tile: w[j] = W[wo+j][lane] (coalesced)
        float w[16];
        #pragma unroll
        for (int j = 0; j < 16; ++j) w[j] = Wm[(wo + j) * 64 + lane];

        float acc0[16], acc1[16];
        #pragma unroll
        for (int j = 0; j < 16; ++j) { acc0[j] = 0.f; acc1[j] = 0.f; }

        #pragma unroll 8
        for (int c = 0; c < 64; ++c) {           // ascending -> bit-identical
            const float2 xv = *(const float2*)(xg + (size_t)c * NPIX);
            #pragma unroll
            for (int j = 0; j < 16; ++j) {
                const float wv = bcast(w[j], c); // SGPR weight
                acc0[j] += wv * xv.x;
                acc1[j] += wv * xv.y;
            }
        }

        const float* bb = bias[m];
        float* o0 = outs[m];
        #pragma unroll
        for (int j4 = 0; j4 < 4; ++j4) {
            float4 v0, v1;
            v0.x = acc0[j4*4+0] + bb[wo + j4*4+0]; v1.x = acc1[j4*4+0] + bb[wo + j4*4+0];
            v0.y = acc0[j4*4+1] + bb[wo + j4*4+1]; v1.y = acc1[j4*4+1] + bb[wo + j4*4+1];
            v0.z = acc0[j4*4+2] + bb[wo + j4*4+2]; v1.z = acc1[j4*4+2] + bb[wo + j4*4+2];
            v0.w = acc0[j4*4+3] + bb[wo + j4*4+3]; v1.w = acc1[j4*4+3] + bb[wo + j4*4+3];
            *(float4*)(o0 + wo + j4*4)      = v0;
            *(float4*)(o0 + 64 + wo + j4*4) = v1;
        }
    }
}

// ---------------------------------------------------------------------------
// K2: conditioning conv (68 -> 17) + channel LayerNorm + lrelu; emits xm.
// Arithmetic unchanged (bit-identical).  xm now written WINDOW-MAJOR so
// k_score's gather becomes contiguous (value-identical relayout).
// ---------------------------------------------------------------------------
__global__ __launch_bounds__(256) void k_cond(
    const float* __restrict__ vs, const float* __restrict__ cg,
    const float* __restrict__ pinW, const float* __restrict__ pinb,
    const float* __restrict__ lnw, const float* __restrict__ lnb,
    float* __restrict__ h1, float* __restrict__ xm)
{
    const int gp = blockIdx.x * 256 + threadIdx.x;
    const int b  = gp >> 16;
    const int p  = gp & 65535;
    const int h  = p >> 8;
    const int w  = p & 255;

    float acc[17];
    #pragma unroll
    for (int oc = 0; oc < 17; ++oc) acc[oc] = pinb[oc];

    const float* vp = vs + (size_t)gp * 64;
    #pragma unroll 8
    for (int c4 = 0; c4 < 16; ++c4) {
        const float4 v4 = *(const float4*)(vp + c4 * 4);
        const float vv[4] = {v4.x, v4.y, v4.z, v4.w};
        #pragma unroll
        for (int k = 0; k < 4; ++k) {
            const int c = c4 * 4 + k;
            #pragma unroll
            for (int oc = 0; oc < 17; ++oc)
                acc[oc] += pinW[oc * 68 + c] * vv[k];
        }
    }
    const float c64 = cg[(b * 2 + 0) * NPIX + p];
    const float c65 = cg[(b * 2 + 1) * NPIX + p];
    const float c66 = -1.f + 2.f * (float)(h & 7) / 7.f;
    const float c67 = -1.f + 2.f * (float)(w & 7) / 7.f;
    #pragma unroll
    for (int oc = 0; oc < 17; ++oc)
        acc[oc] += pinW[oc * 68 + 64] * c64 + pinW[oc * 68 + 65] * c65 +
                   pinW[oc * 68 + 66] * c66 + pinW[oc * 68 + 67] * c67;

    float u = 0.f;
    #pragma unroll
    for (int oc = 0; oc < 17; ++oc) u += acc[oc];
    u *= (1.f / 17.f);
    float s = 0.f;
    #pragma unroll
    for (int oc = 0; oc < 17; ++oc) { const float d = acc[oc] - u; s += d * d; }
    s *= (1.f / 17.f);
    const float rstd = rsqrtf(s + 1e-6f);

    float xsum = 0.f;
    #pragma unroll
    for (int oc = 0; oc < 17; ++oc) {
        float hv = lnw[oc] * (acc[oc] - u) * rstd + lnb[oc];
        hv = (hv >= 0.f) ? hv : 0.1f * hv;
        h1[(b * 17 + oc) * NPIX + p] = hv;
        xsum += hv;
    }
    const int win = (h >> 3) * 32 + (w >> 3);
    const int idx = ((h & 7) << 3) | (w & 7);
    xm[(b << 16) + win * 64 + idx] = xsum * (1.f / 17.f);
}

// ---------------------------------------------------------------------------
// K3: 3x3 conv (17 -> 1) + sigmoid -> sa.  (unchanged)
// ---------------------------------------------------------------------------
__global__ __launch_bounds__(256) void k_sa(
    const float* __restrict__ h1, const float* __restrict__ saW,
    const float* __restrict__ sab, float* __restrict__ sa)
{
    __shared__ float S[17 * 3 * 256];
    const int tid = threadIdx.x;
    const int b   = blockIdx.x >> 8;
    const int row = blockIdx.x & 255;

    for (int i = tid; i < 3264; i += 256) {
        const int ch  = i / 192;
        const int rem = i - ch * 192;
        const int dr  = rem >> 6;
        const int c4  = rem & 63;
        const int rr  = row + dr - 1;
        float4 v = {0.f, 0.f, 0.f, 0.f};
        if ((unsigned)rr < 256u)
            v = *(const float4*)(h1 + ((size_t)(b * 17 + ch)) * NPIX + rr * 256 + c4 * 4);
        *(float4*)&S[(ch * 3 + dr) * 256 + c4 * 4] = v;
    }
    __syncthreads();

    const int w = tid;
    float acc = sab[0];
    #pragma unroll 1
    for (int ch = 0; ch < 17; ++ch) {
        #pragma unroll
        for (int dr = 0; dr < 3; ++dr) {
            const float* Sp = &S[(ch * 3 + dr) * 256];
            const float m  = Sp[w];
            const float l  = (w > 0)   ? Sp[w - 1] : 0.f;
            const float r_ = (w < 255) ? Sp[w + 1] : 0.f;
            const float* Wp = saW + (ch * 3 + dr) * 3;
            acc += Wp[0] * l + Wp[1] * m + Wp[2] * r_;
        }
    }
    sa[b * NPIX + row * 256 + w] = 1.f / (1.f + __expf(-acc));
}

// ---------------------------------------------------------------------------
// K4: window scoring MLP + stable-argsort partition.  xm is window-major ->
// each thread reads its own 64 contiguous floats via float4.  Accumulation
// order over tt (0..63 ascending) and all arithmetic unchanged ->
// bit-identical scores -> identical partition.
// ---------------------------------------------------------------------------
__global__ __launch_bounds__(1024) void k_score_select(
    const float* __restrict__ xm,
    const float* __restrict__ m1W, const float* __restrict__ m1b,
    const float* __restrict__ m2W, const float* __restrict__ m2b,
    int* __restrict__ flag, int* __restrict__ kept)
{
    __shared__ float sc[NW];
    const int b = blockIdx.x;
    const int t = threadIdx.x;

    float z[8];
    #pragma unroll
    for (int jj = 0; jj < 8; ++jj) z[jj] = m1b[jj];

    const float* xw = xm + (b << 16) + t * 64;
    #pragma unroll 4
    for (int t4 = 0; t4 < 16; ++t4) {
        const float4 v4 = *(const float4*)(xw + t4 * 4);
        const float vv[4] = {v4.x, v4.y, v4.z, v4.w};
        #pragma unroll
        for (int k = 0; k < 4; ++k) {
            const int tt = t4 * 4 + k;           // ascending 0..63
            #pragma unroll
            for (int jj = 0; jj < 8; ++jj)
                z[jj] += m1W[jj * 64 + tt] * vv[k];
        }
    }
    #pragma unroll
    for (int jj = 0; jj < 8; ++jj) z[jj] = (z[jj] >= 0.f) ? z[jj] : 0.1f * z[jj];

    float l0 = m2b[0], l1 = m2b[1];
    #pragma unroll
    for (int jj = 0; jj < 8; ++jj) { l0 += m2W[jj] * z[jj]; l1 += m2W[8 + jj] * z[jj]; }
    const float mx = fmaxf(l0, l1);
    const float e0 = expf(l0 - mx), e1 = expf(l1 - mx);
    sc[t] = e0 / (e0 + e1);
    __syncthreads();

    const float s = sc[t];
    int cnt = 0;
    for (int jq = 0; jq < NW; jq += 4) {
        const float4 s4 = *(const float4*)&sc[jq];
        cnt += (s4.x > s) || (s4.x == s && (jq + 0) < t);
        cnt += (s4.y > s) || (s4.y == s && (jq + 1) < t);
        cnt += (s4.z > s) || (s4.z == s && (jq + 2) < t);
        cnt += (s4.w > s) || (s4.w == s && (jq + 3) < t);
    }
    flag[b * NW + t] = (cnt < KEEP) ? 1 : 0;
    if (cnt < KEEP) kept[b * KEEP + cnt] = t;
}

// ---------------------------------------------------------------------------
// K5: windowed attention.  ROUND-5: register-broadcast core, ZERO LDS, no
// barriers.  Round-4 diagnosis: the LDS-broadcast K/V reads moved 4.8 GB on
// the LDS return bus (53 TB/s ~= ceiling) because a uniform b128 still
// returns 1KB/instr.  New design: block = 1 wave = (window, head); per
// 4-key group the wave loads K/V lane-distributed straight from global
// (lane (sub,d_) holds element (px=4g+sub, ch=choff+d_); 4x64B segments,
// L2-resident) and broadcasts via v_readlane.  OOB keys get K=V=0
// (predicated), matching the reference's zero-padded unfold.
// Key order (px 0..143 ascending) and per-key FP sequence (s = srow+cw,
// ascending-d dot, sum += e, ascending-d PV) are instruction-identical to
// round 3 -> bit-identical amix.  amix aliases qs: this block reads only
// its own (window, choff) q slice and writes the same slice at the end.
// ---------------------------------------------------------------------------
__global__ __launch_bounds__(64) void k_attn(
    const float* __restrict__ qs, const float* __restrict__ ks,
    const float* __restrict__ vs, const int* __restrict__ kept,
    const float* __restrict__ relh, const float* __restrict__ relw,
    float* __restrict__ amix)
{
    const int b    = blockIdx.z;
    const int head = blockIdx.y;
    const int win  = kept[b * KEEP + blockIdx.x];
    const int wy = win >> 5, wx = win & 31;
    const int lane = threadIdx.x;
    const int choff = head * 16;
    const size_t bbase = (size_t)b * NPIX;
    const int px0 = (wy * 8) * 256 + wx * 8;
    const int qrow = lane >> 3, qcol = lane & 7;
    const int sub = lane >> 4, d_ = lane & 15;

    // ---- q direct from global (same values as prior rounds, x0.25) ----
    float q[16];
    {
        const float* qp = qs + (bbase + px0 + qrow * 256 + qcol) * 64 + choff;
        #pragma unroll
        for (int j4 = 0; j4 < 4; ++j4) {
            const float4 v = *(const float4*)(qp + j4 * 4);
            q[j4 * 4 + 0] = v.x * 0.25f; q[j4 * 4 + 1] = v.y * 0.25f;
            q[j4 * 4 + 2] = v.z * 0.25f; q[j4 * 4 + 3] = v.w * 0.25f;
        }
    }

    // ---- column rel-pos coefficients (identical arithmetic) ----
    float cw[12];
    #pragma unroll
    for (int k = 0; k < 12; ++k) {
        const float* rw = relw + (k - qcol + 11) * 16;
        float sw = 0.f;
        #pragma unroll
        for (int j4 = 0; j4 < 4; ++j4) {
            const float4 w4 = *(const float4*)(rw + j4 * 4);
            sw += q[j4*4+0]*w4.x + q[j4*4+1]*w4.y + q[j4*4+2]*w4.z + q[j4*4+3]*w4.w;
        }
        cw[k] = sw;
    }

    const int wy8 = wy * 8 - 2, wx8 = wx * 8 - 2;
    const int laneoff = choff + d_;

    float sum = 0.f;
    float vo[16];
    #pragma unroll
    for (int d = 0; d < 16; ++d) vo[d] = 0.f;

    #pragma unroll 1
    for (int r = 0; r < 12; ++r) {               // patch row (12 keys each)
        const int ry = wy8 + r;
        const bool rowok = (unsigned)ry < 256u;

        // row rel-pos coefficient (same instruction sequence as round 3)
        const float* rh = relh + (r - qrow + 11) * 16;
        float srow = 0.f;
        #pragma unroll
        for (int j4 = 0; j4 < 4; ++j4) {
            const float4 h4 = *(const float4*)(rh + j4 * 4);
            srow += q[j4*4+0]*h4.x + q[j4*4+1]*h4.y + q[j4*4+2]*h4.z + q[j4*4+3]*h4.w;
        }

        #pragma unroll
        for (int gi = 0; gi < 3; ++gi) {         // 4-key groups within the row
            const int cx = wx8 + 4 * gi + sub;   // this lane's key column
            float kg = 0.f, vg = 0.f;
            if (rowok && (unsigned)cx < 256u) {
                const size_t a = (bbase + (size_t)(ry * 256 + cx)) * 64 + laneoff;
                kg = ks[a];
                vg = vs[a];
            }
            #pragma unroll
            for (int kk = 0; kk < 4; ++kk) {     // key col = 4*gi + kk (literal)
                float s = srow + cw[4 * gi + kk];
                #pragma unroll
                for (int d = 0; d < 16; ++d)     // ascending d, same FP order
                    s += bcast(kg, kk * 16 + d) * q[d];
                const float e = __expf(s);
                sum += e;
                #pragma unroll
                for (int d = 0; d < 16; ++d)     // ascending d, same FP order
                    vo[d] += e * bcast(vg, kk * 16 + d);
            }
        }
    }

    // ---- epilogue: normalize, direct store of this head's 16-ch slice ----
    const float inv = 1.f / sum;
    float* op = amix + (bbase + px0 + qrow * 256 + qcol) * 64 + choff;
    #pragma unroll
    for (int j4 = 0; j4 < 4; ++j4) {
        float4 v;
        v.x = vo[j4*4+0] * inv; v.y = vo[j4*4+1] * inv;
        v.z = vo[j4*4+2] * inv; v.w = vo[j4*4+3] * inv;
        *(float4*)(op + j4 * 4) = v;
    }
}

// ---------------------------------------------------------------------------
// K6: final 1x1 conv (64 -> 64) with fused easy path.  ROUND-5: weights via
// lane-distributed registers + readlane (no W LDS -> no broadcast BW);
// x staged in LDS transposed (per-lane DISTINCT reads = full bus use).
// 2 px per lane.  Per-output FP order (c ascending, +bias) identical.
// ---------------------------------------------------------------------------
__global__ __launch_bounds__(256) void k_out_f(
    const float* __restrict__ amix, const float* __restrict__ vs,
    const float* __restrict__ sa, const int* __restrict__ flag,
    const float* __restrict__ W, const float* __restrict__ bias,
    float* __restrict__ out)
{
    __shared__ float xs[64][130];                // 33.3 KB (pad: even, 8B-aligned pairs)
    __shared__ float smult[128];
    __shared__ int   sflag[128];
    const int tid  = threadIdx.x;
    const int lane = tid & 63;
    const int og   = __builtin_amdgcn_readfirstlane(tid >> 6);
    const int tile = blockIdx.x;                 // 0..1023
    const int b    = tile >> 9;
    const int p0   = (tile & 511) << 7;          // 128-px tile
    const int wo   = og * 16;

    if (tid < 128) {
        const int p   = p0 + tid;
        const int h   = p >> 8, w_ = p & 255;
        const int win = (h >> 3) * 32 + (w_ >> 3);
        const int fl  = flag[b * NW + win];
        sflag[tid] = fl;
        smult[tid] = fl ? 1.f : sa[(b << 16) + p];
    }
    __syncthreads();

    // stage 128 px x 64 ch with mult applied; NHWC float4 reads (coalesced),
    // transposed scalar LDS writes
    #pragma unroll
    for (int it = 0; it < 8; ++it) {
        const int i   = it * 256 + tid;
        const int pxl = i >> 4;                  // 0..127
        const int c4  = i & 15;
        const int gpl = (b << 16) + p0 + pxl;
        const float* src = (sflag[pxl] ? amix : vs) + (size_t)gpl * 64;
        const float m = smult[pxl];
        const float4 v = *(const float4*)(src + c4 * 4);
        xs[c4 * 4 + 0][pxl] = v.x * m;
        xs[c4 * 4 + 1][pxl] = v.y * m;
        xs[c4 * 4 + 2][pxl] = v.z * m;
        xs[c4 * 4 + 3][pxl] = v.w * m;
    }
    __syncthreads();

    // lane-distributed weights
    float w[16];
    #pragma unroll
    for (int j = 0; j < 16; ++j) w[j] = W[(wo + j) * 64 + lane];

    float acc0[16], acc1[16];
    #pragma unroll
    for (int j = 0; j < 16; ++j) { acc0[j] = 0.f; acc1[j] = 0.f; }

    #pragma unroll 8
    for (int c = 0; c < 64; ++c) {               // ascending -> bit-identical
        const float2 xv = *(const float2*)&xs[c][2 * lane];
        #pragma unroll
        for (int j = 0; j < 16; ++j) {
            const float wv = bcast(w[j], c);
            acc0[j] += wv * xv.x;
            acc1[j] += wv * xv.y;
        }
    }

    const int p    = p0 + 2 * lane;
    const int base = (b << 6) * NPIX + p;
    #pragma unroll
    for (int j = 0; j < 16; ++j) {
        const float bj = bias[wo + j];
        out[base +     (wo + j) * NPIX] = acc0[j] + bj;
        out[base + 1 + (wo + j) * NPIX] = acc1[j] + bj;
    }
}

// ---------------------------------------------------------------------------
extern "C" void kernel_launch(void* const* d_in, const int* in_sizes, int n_in,
                              void* d_out, int out_size, void* d_ws, size_t ws_size,
                              hipStream_t stream)
{
    const float* x    = (const float*)d_in[0];
    const float* cg   = (const float*)d_in[1];
    const float* Wq   = (const float*)d_in[2];
    const float* bq   = (const float*)d_in[3];
    const float* Wk   = (const float*)d_in[4];
    const float* bk   = (const float*)d_in[5];
    const float* Wv   = (const float*)d_in[6];
    const float* bv   = (const float*)d_in[7];
    const float* Wout = (const float*)d_in[8];
    const float* bout = (const float*)d_in[9];
    const float* relh = (const float*)d_in[10];
    const float* relw = (const float*)d_in[11];
    const float* pinW = (const float*)d_in[12];
    const float* pinb = (const float*)d_in[13];
    const float* lnw  = (const float*)d_in[14];
    const float* lnb  = (const float*)d_in[15];
    const float* saW  = (const float*)d_in[16];
    const float* sab  = (const float*)d_in[17];
    const float* m1W  = (const float*)d_in[18];
    const float* m1b  = (const float*)d_in[19];
    const float* m2W  = (const float*)d_in[20];
    const float* m2b  = (const float*)d_in[21];
    float* out = (float*)d_out;

    // workspace layout (floats); qs doubles as the assembled "amix" tensor
    float* ws    = (float*)d_ws;
    float* qs    = ws;                       // 64*NPIXT (NHWC, aliased amix)
    float* ks    = qs + 8388608;             // NHWC
    float* vs    = ks + 8388608;             // NHWC
    float* h1    = vs + 8388608;             // 17 * NPIXT (NCHW)
    float* xm    = h1 + 17 * NPIXT;          // NPIXT (window-major)
    float* sa    = xm + NPIXT;               // NPIXT
    int*   flag  = (int*)(sa + NPIXT);       // 2048
    int*   kept  = flag + 2048;              // 1024

    k_qkv         <<<1024, 256, 0, stream>>>(x, Wq, bq, Wk, bk, Wv, bv, qs, ks, vs);
    k_cond        <<<NPIXT / 256, 256, 0, stream>>>(vs, cg, pinW, pinb, lnw, lnb, h1, xm);
    k_sa          <<<512, 256, 0, stream>>>(h1, saW, sab, sa);
    k_score_select<<<2, 1024, 0, stream>>>(xm, m1W, m1b, m2W, m2b, flag, kept);
    k_attn        <<<dim3(KEEP, 4, 2), 64, 0, stream>>>(qs, ks, vs, kept, relh, relw, qs);
    k_out_f       <<<1024, 256, 0, stream>>>(qs, vs, sa, flag, Wout, bout, out);
}